// Round 5
// baseline (455.458 us; speedup 1.0000x reference)
//
#include <hip/hip_runtime.h>
#include <hip/hip_bf16.h>

// channel_Encoding_Block — split-bf16 MFMA stage-A + f32 VALU attn/proj.
// R5: LDS shrunk to EXACTLY 32768 B -> 5 blocks/CU (was 39424 -> 4).
//   * W image frag-linear (lane*16B), emitted by wc_kernel in frag order.
//   * xs hi/lo frag-linear.
//   * qS/kT/vT unpadded [32][32] f32 with XOR bank swizzle on both sides.
//   * g/b/gates moved to registers (global loads at kernel top).
//
//  x[b,c,t,d,i] (i fastest). emb[b,c,i,t,j] = sum_d x[b,c,t,d,i]*pos[c,j,d].
//  out[b,c,t,j,i] = sig(ys_c[b,i,t]) * sig(ln_y[b,c,i,t,j]) * x[b,c,t,j,i].
//  qkv = x @ Wc^T with Wc = W @ pos^T; B = [k|v|q(scaled)|pos] split bf16:
//    D = aH*bH + aH*bL + aL*bH   (3 MFMAs, rel err ~2^-16)
//
//  Phase1: 768 blocks (b,c); Phase2: 24576 blocks (b,c,i), XCD-swizzled.

using bf16 = __hip_bfloat16;
typedef float v2f __attribute__((ext_vector_type(2)));
using short8 = __attribute__((ext_vector_type(8))) short;   // 8 bf16 (4 VGPRs)
using f32x4  = __attribute__((ext_vector_type(4))) float;

__device__ __forceinline__ v2f pk_fma(v2f acc, v2f a, v2f b) {
  asm("v_pk_fma_f32 %0, %1, %2, %0" : "+v"(acc) : "v"(a), "v"(b));
  return acc;
}

template <int CTRL>
__device__ __forceinline__ float dpp_add(float x) {
  return x + __int_as_float(
      __builtin_amdgcn_mov_dpp(__float_as_int(x), CTRL, 0xF, 0xF, true));
}

__device__ __forceinline__ ushort bf16_rne(float f) {
  uint u = __float_as_uint(f);
  return (ushort)((u + 0x7FFFu + ((u >> 16) & 1u)) >> 16);
}
__device__ __forceinline__ void split2(float x, ushort& h, ushort& l) {
  h = bf16_rne(x);
  l = bf16_rne(x - __uint_as_float((uint)h << 16));
}

// frag-linear index (ushort units) for a [32][32] bf16 matrix tiled 2x(16x32):
// lane l of tile T reads chunk l (16B): row=l&15, k=(l>>4)*8..+7.
__device__ __forceinline__ int frag_idx(int row, int k) {
  return ((row >> 4) << 9) + (((row & 15) + ((k >> 3) << 4)) << 3) + (k & 7);
}

struct __align__(16) SMem {
  ushort xsH[1024];    // 2048B  x hi, frag-linear
  ushort xsL[1024];    // 2048B  x lo
  union {
    ushort W[8192];    // 16384B: hi tiles 0..7 at tile*512+lane*8; lo at +4096
    struct {
      float esT[32][36];   // E^T [j][t]
      float aoF[32][36];   // attn out [t][f]
      float w0s[32][36];   // w0 [j][f]
    } s;                   // 13824B
  } u;
  float qS[1024];      // 4096B  q[t][c]:  byte = (t*128+c*4) ^ (((t>>1)&7)<<4)
  float kT[1024];      // 4096B  k[r][s]:  byte = (r*128+s*4) ^ ((r&7)<<4)
  float vT[1024];      // 4096B  v[r][s]:  same swizzle
};                     // total 32768B -> 5 blocks/CU

__device__ __forceinline__ float* swz_q(float* base, int t, int c) {
  return (float*)((char*)base + (((t << 7) + (c << 2)) ^ (((t >> 1) & 7) << 4)));
}
__device__ __forceinline__ const float* swz_qc(const float* base, int t, int c) {
  return (const float*)((const char*)base +
                        (((t << 7) + (c << 2)) ^ (((t >> 1) & 7) << 4)));
}
__device__ __forceinline__ float* swz_kv(float* base, int r, int s) {
  return (float*)((char*)base + (((r << 7) + (s << 2)) ^ ((r & 7) << 4)));
}
__device__ __forceinline__ const float* swz_kvc(const float* base, int r, int s) {
  return (const float*)((const char*)base +
                        (((r << 7) + (s << 2)) ^ ((r & 7) << 4)));
}

// ------------------------------------------------- wc kernel (runs once)
// Emits per-set 16384B frag-linear image: hi tiles 0..7, lo at +8192B.
// Row n: 0..31 k (cc=n), 32..63 v, 64..95 q (pre-scaled), 96..127 pos.
__global__ __launch_bounds__(256) void wc_kernel(
    const float* __restrict__ pos_y, const float* __restrict__ wqvk_y,
    const float* __restrict__ wqvk_x, ushort* __restrict__ wc2)
{
  const int n6 = blockIdx.x;         // 0..5: n6<3 -> y-set (c=n6), else x-set
  const int c = n6 % 3, xset = n6 / 3;
  const float* W = (xset ? wqvk_x : wqvk_y) + c * 3072;   // [96][32] (f,j)
  const float* P = pos_y + (xset ? 2 : c) * 1024;         // [32][32] (j,d)
  __shared__ float Ws[96][33];
  __shared__ float Ps[32][33];
  const int tid = threadIdx.x;
#pragma unroll
  for (int k = 0; k < 12; ++k) {
    const int e = tid * 12 + k;
    Ws[e >> 5][e & 31] = W[e];
  }
#pragma unroll
  for (int k = 0; k < 4; ++k) {
    const int e = tid * 4 + k;
    Ps[e >> 5][e & 31] = P[e];
  }
  __syncthreads();
  const int n = tid & 127, half = tid >> 7;   // row n, k range 16*half..+15
  float src[16];
  if (n >= 96) {
    const int j = n - 96;
#pragma unroll
    for (int dd = 0; dd < 16; ++dd) src[dd] = Ps[j][16 * half + dd];
  } else {
    const int sidx = n >> 5;          // 0=k,1=v,2=q
    const int m = n & 31, dh = m & 3, h = m >> 2;
    const int f = dh * 24 + (sidx == 0 ? 8 : (sidx == 1 ? 16 : 0)) + h;
    const float sc = (sidx == 2) ? 0.72134752f : 1.0f;  // 0.5*log2(e) on q
#pragma unroll
    for (int dd = 0; dd < 16; ++dd) {
      float s = 0.f;
      for (int j = 0; j < 32; ++j) s += Ws[f][j] * Ps[j][16 * half + dd];
      src[dd] = s * sc;
    }
  }
  ushort* base = wc2 + (size_t)n6 * 8192;
  const int tile = n >> 4, rr = n & 15;
#pragma unroll
  for (int dd = 0; dd < 16; ++dd) {
    const int k = 16 * half + dd;
    const int off = tile * 512 + ((rr + ((k >> 3) << 4)) << 3) + (k & 7);
    ushort hh, ll;
    split2(src[dd], hh, ll);
    base[off]        = hh;
    base[4096 + off] = ll;
  }
}

// -------------------------------------------------------------- table load
__device__ __forceinline__ void load_tables(
    SMem& sm, int tid, const float* __restrict__ xbc, int i,
    const ushort* __restrict__ wc2)
{
  const int t = tid >> 3, dq = (tid & 7) * 4;
  float xv[4];
#pragma unroll
  for (int k = 0; k < 4; ++k) xv[k] = xbc[(t * 32 + dq + k) * 32 + i];
  ushort hs[4], ls[4];
#pragma unroll
  for (int k = 0; k < 4; ++k) split2(xv[k], hs[k], ls[k]);
  const int off = frag_idx(t, dq);            // 4 consecutive ushorts, 8B-aligned
  *(short4*)&sm.xsH[off] = make_short4((short)hs[0], (short)hs[1],
                                       (short)hs[2], (short)hs[3]);
  *(short4*)&sm.xsL[off] = make_short4((short)ls[0], (short)ls[1],
                                       (short)ls[2], (short)ls[3]);
  // W image: linear 64B/thread copy
  {
    const float4* src = (const float4*)(wc2 + tid * 32);
    float4 r0 = src[0], r1 = src[1], r2 = src[2], r3 = src[3];
    float4* dst = (float4*)(sm.u.W + tid * 32);
    dst[0] = r0; dst[1] = r1; dst[2] = r2; dst[3] = r3;
  }
}

// sigmoid(LayerNorm(E + MHSA(E))): thread's 2x2 outputs at rows {g,g+16},
// cols {l,l+16} (g=tid>>4, l=tid&15). g0/b0/g1/b1: LN gamma/beta (pre *log2e).
__device__ __forceinline__ void mhsa_core(SMem& sm, int tid,
                                          const float* __restrict__ w0g,
                                          float g0, float b0, float g1, float b1,
                                          float sig_out[2][2])
{
  const int wv = tid >> 6, lane = tid & 63;
  const int lr = lane & 15, lk = lane >> 4;
  const int mt = wv >> 1;             // wave's token tile (0,1)
  const int qe = wv & 1;              // 0: k/v tiles; 1: q/E tiles
  const int t0 = mt * 16 + lk * 4;    // C rows (4 consecutive tokens)
  f32x4 eC0 = {0.f,0.f,0.f,0.f}, eC1 = {0.f,0.f,0.f,0.f};

  // ---- stage A: E+qkv on the matrix pipe (split-bf16, 3 MFMA/tile) ----
  {
    short8 aH = *(const short8*)&sm.xsH[mt * 512 + lane * 8];
    short8 aL = *(const short8*)&sm.xsL[mt * 512 + lane * 8];
    f32x4 acc[4];
#pragma unroll
    for (int q = 0; q < 4; ++q) {
      const int tile = qe * 4 + q;
      short8 bH = *(const short8*)&sm.u.W[tile * 512 + lane * 8];
      short8 bL = *(const short8*)&sm.u.W[4096 + tile * 512 + lane * 8];
      f32x4 c = {0.f, 0.f, 0.f, 0.f};
      c = __builtin_amdgcn_mfma_f32_16x16x32_bf16(aH, bH, c, 0, 0, 0);
      c = __builtin_amdgcn_mfma_f32_16x16x32_bf16(aH, bL, c, 0, 0, 0);
      c = __builtin_amdgcn_mfma_f32_16x16x32_bf16(aL, bH, c, 0, 0, 0);
      acc[q] = c;
    }
    if (qe == 0) {            // k rows (cc 0..31), v rows
      *(f32x4*)swz_kv(sm.kT, lr,      t0) = acc[0];
      *(f32x4*)swz_kv(sm.kT, lr + 16, t0) = acc[1];
      *(f32x4*)swz_kv(sm.vT, lr,      t0) = acc[2];
      *(f32x4*)swz_kv(sm.vT, lr + 16, t0) = acc[3];
    } else {                  // q rows -> qS scatter; E -> regs
#pragma unroll
      for (int r = 0; r < 4; ++r) {
        *swz_q(sm.qS, t0 + r, lr)      = acc[0][r];
        *swz_q(sm.qS, t0 + r, lr + 16) = acc[1][r];
      }
      eC0 = acc[2]; eC1 = acc[3];
    }
  }
  // deferred W0 load (HBM latency overlaps barrier + stores)
  float4 w0v = *(const float4*)&w0g[tid * 4];
  __syncthreads();
  // weight buffer dead -> overlay: E^T, then w0
  if (qe == 1) {
    *(f32x4*)&sm.u.s.esT[lr][t0]      = eC0;   // esT[j][t..t+3]
    *(f32x4*)&sm.u.s.esT[lr + 16][t0] = eC1;
  }
  { const int e = tid * 4; *(float4*)&sm.u.s.w0s[e >> 5][e & 31] = w0v; }

  // ---- stage 2: attention, 4t x 8s per lane; quad-DPP reductions ----
  {
    const int h = tid >> 5, tg2 = (tid >> 2) & 7, sg2 = tid & 3;
    const int ta = 4 * tg2, s0 = 8 * sg2;
    float4 qr0 = *(const float4*)swz_qc(sm.qS, ta + 0, 4 * h);
    float4 qr1 = *(const float4*)swz_qc(sm.qS, ta + 1, 4 * h);
    float4 qr2 = *(const float4*)swz_qc(sm.qS, ta + 2, 4 * h);
    float4 qr3 = *(const float4*)swz_qc(sm.qS, ta + 3, 4 * h);
    const float qa_[4][4] = {
        {qr0.x, qr0.y, qr0.z, qr0.w},
        {qr1.x, qr1.y, qr1.z, qr1.w},
        {qr2.x, qr2.y, qr2.z, qr2.w},
        {qr3.x, qr3.y, qr3.z, qr3.w}};
    v2f sc[4][4];
#pragma unroll
    for (int kk = 0; kk < 4; ++kk)
#pragma unroll
      for (int sp2 = 0; sp2 < 4; ++sp2) sc[kk][sp2] = v2f{0.f, 0.f};
#pragma unroll
    for (int dh = 0; dh < 4; ++dh) {
      float4 ka = *(const float4*)swz_kvc(sm.kT, 4 * h + dh, s0);
      float4 kb = *(const float4*)swz_kvc(sm.kT, 4 * h + dh, s0 + 4);
      v2f k0{ka.x, ka.y}, k1{ka.z, ka.w}, k2{kb.x, kb.y}, k3{kb.z, kb.w};
#pragma unroll
      for (int kk = 0; kk < 4; ++kk) {
        v2f qv{qa_[kk][dh], qa_[kk][dh]};
        sc[kk][0] = pk_fma(sc[kk][0], qv, k0);
        sc[kk][1] = pk_fma(sc[kk][1], qv, k1);
        sc[kk][2] = pk_fma(sc[kk][2], qv, k2);
        sc[kk][3] = pk_fma(sc[kk][3], qv, k3);
      }
    }
    float inv[4];
#pragma unroll
    for (int kk = 0; kk < 4; ++kk) {
#pragma unroll
      for (int sp2 = 0; sp2 < 4; ++sp2) {
        sc[kk][sp2][0] = exp2f(sc[kk][sp2][0]);
        sc[kk][sp2][1] = exp2f(sc[kk][sp2][1]);
      }
      v2f dv = sc[kk][0] + sc[kk][1];
      v2f dw = sc[kk][2] + sc[kk][3];
      dv += dw;
      float dn = dv[0] + dv[1];
      dn = dpp_add<0xB1>(dn);
      dn = dpp_add<0x4E>(dn);
      inv[kk] = __fdividef(1.0f, dn);
    }
    v2f pv[4][4];
#pragma unroll
    for (int kk = 0; kk < 4; ++kk)
#pragma unroll
      for (int dh = 0; dh < 4; ++dh) pv[kk][dh] = v2f{0.f, 0.f};
#pragma unroll
    for (int dh = 0; dh < 4; ++dh) {
      float4 va = *(const float4*)swz_kvc(sm.vT, 4 * h + dh, s0);
      float4 vb = *(const float4*)swz_kvc(sm.vT, 4 * h + dh, s0 + 4);
      v2f v0{va.x, va.y}, v1{va.z, va.w}, v2v{vb.x, vb.y}, v3{vb.z, vb.w};
#pragma unroll
      for (int kk = 0; kk < 4; ++kk) {
        pv[kk][dh] = pk_fma(pv[kk][dh], sc[kk][0], v0);
        pv[kk][dh] = pk_fma(pv[kk][dh], sc[kk][1], v1);
        pv[kk][dh] = pk_fma(pv[kk][dh], sc[kk][2], v2v);
        pv[kk][dh] = pk_fma(pv[kk][dh], sc[kk][3], v3);
      }
    }
    float ov[4][4];
#pragma unroll
    for (int kk = 0; kk < 4; ++kk)
#pragma unroll
      for (int dh = 0; dh < 4; ++dh) {
        float o = pv[kk][dh][0] + pv[kk][dh][1];
        o = dpp_add<0xB1>(o);
        o = dpp_add<0x4E>(o);
        ov[kk][dh] = o;
      }
    if (sg2 == 0) {
#pragma unroll
      for (int kk = 0; kk < 4; ++kk) {
        *(float4*)&sm.u.s.aoF[ta + kk][4 * h] = make_float4(
            ov[kk][0] * inv[kk], ov[kk][1] * inv[kk],
            ov[kk][2] * inv[kk], ov[kk][3] * inv[kk]);
      }
    }
  }
  __syncthreads();

  // ---- stage 3: proj + residual + LN (DPP) + sigmoid, 2x2 tile ----
  {
    const int g = tid >> 4, l = tid & 15;
    v2f a00{0.f,0.f}, a01{0.f,0.f}, a10{0.f,0.f}, a11{0.f,0.f};
#pragma unroll
    for (int f4 = 0; f4 < 8; ++f4) {
      float4 u0 = *(const float4*)&sm.u.s.aoF[g][4 * f4];       // broadcast
      float4 u1 = *(const float4*)&sm.u.s.aoF[g + 16][4 * f4];
      float4 w0 = *(const float4*)&sm.u.s.w0s[l][4 * f4];       // w0[j][f]
      float4 w1 = *(const float4*)&sm.u.s.w0s[l + 16][4 * f4];
      a00 = pk_fma(a00, v2f{u0.x, u0.y}, v2f{w0.x, w0.y});
      a00 = pk_fma(a00, v2f{u0.z, u0.w}, v2f{w0.z, w0.w});
      a01 = pk_fma(a01, v2f{u0.x, u0.y}, v2f{w1.x, w1.y});
      a01 = pk_fma(a01, v2f{u0.z, u0.w}, v2f{w1.z, w1.w});
      a10 = pk_fma(a10, v2f{u1.x, u1.y}, v2f{w0.x, w0.y});
      a10 = pk_fma(a10, v2f{u1.z, u1.w}, v2f{w0.z, w0.w});
      a11 = pk_fma(a11, v2f{u1.x, u1.y}, v2f{w1.x, w1.y});
      a11 = pk_fma(a11, v2f{u1.z, u1.w}, v2f{w1.z, w1.w});
    }
    float rr[2][2];
    rr[0][0] = a00[0] + a00[1] + sm.u.s.esT[l][g];
    rr[0][1] = a01[0] + a01[1] + sm.u.s.esT[l + 16][g];
    rr[1][0] = a10[0] + a10[1] + sm.u.s.esT[l][g + 16];
    rr[1][1] = a11[0] + a11[1] + sm.u.s.esT[l + 16][g + 16];
    float s1a = rr[0][0] + rr[0][1], s1b = rr[1][0] + rr[1][1];
    float s2a = rr[0][0]*rr[0][0] + rr[0][1]*rr[0][1];
    float s2b = rr[1][0]*rr[1][0] + rr[1][1]*rr[1][1];
    s1a = dpp_add<0xB1>(s1a); s1a = dpp_add<0x4E>(s1a);
    s1a = dpp_add<0x124>(s1a); s1a = dpp_add<0x128>(s1a);
    s2a = dpp_add<0xB1>(s2a); s2a = dpp_add<0x4E>(s2a);
    s2a = dpp_add<0x124>(s2a); s2a = dpp_add<0x128>(s2a);
    s1b = dpp_add<0xB1>(s1b); s1b = dpp_add<0x4E>(s1b);
    s1b = dpp_add<0x124>(s1b); s1b = dpp_add<0x128>(s1b);
    s2b = dpp_add<0xB1>(s2b); s2b = dpp_add<0x4E>(s2b);
    s2b = dpp_add<0x124>(s2b); s2b = dpp_add<0x128>(s2b);
    const float mua = s1a * (1.0f / 32.0f), mub = s1b * (1.0f / 32.0f);
    const float ra = rsqrtf(s2a * (1.0f / 32.0f) - mua * mua + 1e-5f);
    const float rb = rsqrtf(s2b * (1.0f / 32.0f) - mub * mub + 1e-5f);
    sig_out[0][0] = __fdividef(1.0f, 1.0f + exp2f(-((rr[0][0] - mua) * ra * g0 + b0)));
    sig_out[0][1] = __fdividef(1.0f, 1.0f + exp2f(-((rr[0][1] - mua) * ra * g1 + b1)));
    sig_out[1][0] = __fdividef(1.0f, 1.0f + exp2f(-((rr[1][0] - mub) * rb * g0 + b0)));
    sig_out[1][1] = __fdividef(1.0f, 1.0f + exp2f(-((rr[1][1] - mub) * rb * g1 + b1)));
  }
}

__global__ __launch_bounds__(256, 5) void phase1_kernel(
    const float* __restrict__ x, const ushort* __restrict__ wc2,
    const float* __restrict__ w0_x,
    const float* __restrict__ g_x, const float* __restrict__ b_x,
    bf16* __restrict__ gates)
{
  __shared__ SMem sm;
  const int tid = threadIdx.x;
  const int n = blockIdx.x;          // 768 = 256*3
  const int c = n % 3, b = n / 3;
  const int l = tid & 15;
  const float L2E = 1.44269504f;
  const float g0 = g_x[l] * L2E,      b0 = b_x[l] * L2E;
  const float g1 = g_x[l + 16] * L2E, b1 = b_x[l + 16] * L2E;
  const float* xbc = x + (size_t)(b * 3 + 2) * 32768;   // channel 2
  load_tables(sm, tid, xbc, 31, wc2 + (size_t)(3 + c) * 8192);
  __syncthreads();
  float sig[2][2];
  mhsa_core(sm, tid, w0_x + c * 1024, g0, b0, g1, b1, sig);
  const int g = tid >> 4;
#pragma unroll
  for (int u = 0; u < 2; ++u)
#pragma unroll
    for (int v = 0; v < 2; ++v)
      gates[((c * 256 + b) * 32 + g + 16 * u) * 32 + l + 16 * v] =
          __float2bfloat16(sig[u][v]);
}

__global__ __launch_bounds__(256, 5) void phase2_kernel(
    const float* __restrict__ x, const ushort* __restrict__ wc2,
    const float* __restrict__ w0_y,
    const float* __restrict__ g_y, const float* __restrict__ b_y,
    const bf16* __restrict__ gates, float* __restrict__ out)
{
  __shared__ SMem sm;
  const int tid = threadIdx.x;
  const int n = blockIdx.x;                    // 24576
  const int p = (n & 7) * 3072 + (n >> 3);     // XCD swizzle
  const int i = p & 31, bc = p >> 5;
  const int c = bc % 3, b = bc / 3;
  const int g = tid >> 4, l = tid & 15;
  const float L2E = 1.44269504f;
  const float g0 = g_y[l] * L2E,      b0 = b_y[l] * L2E;
  const float g1 = g_y[l + 16] * L2E, b1 = b_y[l + 16] * L2E;
  const int gbase = ((c * 256 + b) * 32 + i) * 32;
  const float sg0 = __bfloat162float(gates[gbase + g]);        // gate rows
  const float sg1 = __bfloat162float(gates[gbase + g + 16]);
  const float* xbc = x + (size_t)bc * 32768;
  load_tables(sm, tid, xbc, i, wc2 + (size_t)c * 8192);
  __syncthreads();
  float sig[2][2];
  mhsa_core(sm, tid, w0_y + c * 1024, g0, b0, g1, b1, sig);
  float* ob = out + (size_t)bc * 32768 + i;
#pragma unroll
  for (int u = 0; u < 2; ++u) {
    const int r = g + 16 * u;
    const float sgv = (u == 0) ? sg0 : sg1;
#pragma unroll
    for (int v = 0; v < 2; ++v) {
      const int cc = l + 16 * v;
      const int off = frag_idx(r, cc);
      const float xvv = __uint_as_float((uint)sm.xsH[off] << 16) +
                        __uint_as_float((uint)sm.xsL[off] << 16);
      ob[(r * 32 + cc) * 32] = sgv * sig[u][v] * xvv;
    }
  }
}

extern "C" void kernel_launch(void* const* d_in, const int* in_sizes, int n_in,
                              void* d_out, int out_size, void* d_ws, size_t ws_size,
                              hipStream_t stream) {
  const float* x      = (const float*)d_in[0];
  const float* pos_y  = (const float*)d_in[1];
  const float* wqvk_y = (const float*)d_in[2];
  const float* w0_y   = (const float*)d_in[3];
  const float* g_y    = (const float*)d_in[4];
  const float* b_y    = (const float*)d_in[5];
  const float* wqvk_x = (const float*)d_in[6];
  const float* w0_x   = (const float*)d_in[7];
  const float* g_x    = (const float*)d_in[8];
  const float* b_x    = (const float*)d_in[9];
  bf16*   gates = (bf16*)d_ws;                             // 1.5 MB
  ushort* wc2   = (ushort*)((char*)d_ws + 1572864);        // 6*16384 B

  hipLaunchKernelGGL(wc_kernel, dim3(6), dim3(256), 0, stream,
                     pos_y, wqvk_y, wqvk_x, wc2);
  hipLaunchKernelGGL(phase1_kernel, dim3(768), dim3(256), 0, stream,
                     x, wc2, w0_x, g_x, b_x, gates);
  hipLaunchKernelGGL(phase2_kernel, dim3(24576), dim3(256), 0, stream,
                     x, wc2, w0_y, g_y, b_y, gates, (float*)d_out);
}

// Round 6
// 406.626 us; speedup vs baseline: 1.1201x; 1.1201x over previous
//
#include <hip/hip_runtime.h>
#include <hip/hip_bf16.h>

// channel_Encoding_Block — split-bf16 MFMA stage-A + f32 VALU attn/proj.
// R6: 512-thread phase2 blocks, 2 i-values per block sharing one W image.
//     LDS 52224 B -> 3 blocks/CU = 24 waves/CU (was 16). No XOR swizzles
//     (R5 lesson: swizzle VALU + conflicts regressed; exact-32KB 5-block
//     target unreachable due to LDS reservation). Overlays: esT/w0s on dead
//     W region; per-half aoF on own qS (extra barrier after q consumption).
//
//  x[b,c,t,d,i] (i fastest). emb[b,c,i,t,j] = sum_d x[b,c,t,d,i]*pos[c,j,d].
//  out[b,c,t,j,i] = sig(ys_c[b,i,t]) * sig(ln_y[b,c,i,t,j]) * x[b,c,t,j,i].
//  qkv = x @ Wc^T with Wc = W @ pos^T; B = [k|v|q(scaled)|pos] split bf16:
//    D = aH*bH + aH*bL + aL*bH   (3 MFMAs, rel err ~2^-16)
//
//  Phase1: 768 blocks (b,c), 256 thr; Phase2: 12288 blocks, 512 thr, XCD-swz.

using bf16 = __hip_bfloat16;
typedef float v2f __attribute__((ext_vector_type(2)));
using short8 = __attribute__((ext_vector_type(8))) short;   // 8 bf16 (4 VGPRs)
using f32x4  = __attribute__((ext_vector_type(4))) float;

__device__ __forceinline__ v2f pk_fma(v2f acc, v2f a, v2f b) {
  asm("v_pk_fma_f32 %0, %1, %2, %0" : "+v"(acc) : "v"(a), "v"(b));
  return acc;
}

template <int CTRL>
__device__ __forceinline__ float dpp_add(float x) {
  return x + __int_as_float(
      __builtin_amdgcn_mov_dpp(__float_as_int(x), CTRL, 0xF, 0xF, true));
}

__device__ __forceinline__ ushort bf16_rne(float f) {
  uint u = __float_as_uint(f);
  return (ushort)((u + 0x7FFFu + ((u >> 16) & 1u)) >> 16);
}
__device__ __forceinline__ void split2(float x, ushort& h, ushort& l) {
  h = bf16_rne(x);
  l = bf16_rne(x - __uint_as_float((uint)h << 16));
}

// frag-linear index (ushort units) for a [32][32] bf16 matrix tiled 2x(16x32):
// lane l of tile T reads chunk l (16B): row=l&15, k=(l>>4)*8..+7.
__device__ __forceinline__ int frag_idx(int row, int k) {
  return ((row >> 4) << 9) + (((row & 15) + ((k >> 3) << 4)) << 3) + (k & 7);
}

struct __align__(16) Half {
  ushort xsH[1024];      // 2048B x hi, frag-linear
  ushort xsL[1024];      // 2048B x lo
  union {
    float qS[32][36];    // q[t][c]; cols 32/33 = g*log2e / b*log2e (preserved)
    float aoF[32][36];   // overlay after q consumed (writes cols 0..31 only)
  } qa;                  // 4608B
  float kT[32][36];      // 4608B k[r][s]; col32 = gate[t] (phase2)
  float vT[32][36];      // 4608B v[r][s]
};                       // 17920B

struct __align__(16) SMem {
  union {
    ushort W[8192];      // 16384B: hi tiles 0..7 at tile*512+lane*8; lo +4096
    struct { float esT[2][32][36]; float w0s[32][36]; } o;   // 13824B
  } u;
  Half h[2];             // 35840B
};                       // 52224B -> 3 blocks/CU (512 thr) = 24 waves/CU

// ------------------------------------------------- wc kernel (runs once)
// Emits per-set 16384B frag-linear image: hi tiles 0..7, lo at +8192B.
// Row n: 0..31 k (cc=n), 32..63 v, 64..95 q (pre-scaled), 96..127 pos.
__global__ __launch_bounds__(256) void wc_kernel(
    const float* __restrict__ pos_y, const float* __restrict__ wqvk_y,
    const float* __restrict__ wqvk_x, ushort* __restrict__ wc2)
{
  const int n6 = blockIdx.x;         // 0..5: n6<3 -> y-set (c=n6), else x-set
  const int c = n6 % 3, xset = n6 / 3;
  const float* W = (xset ? wqvk_x : wqvk_y) + c * 3072;   // [96][32] (f,j)
  const float* P = pos_y + (xset ? 2 : c) * 1024;         // [32][32] (j,d)
  __shared__ float Ws[96][33];
  __shared__ float Ps[32][33];
  const int tid = threadIdx.x;
#pragma unroll
  for (int k = 0; k < 12; ++k) {
    const int e = tid * 12 + k;
    Ws[e >> 5][e & 31] = W[e];
  }
#pragma unroll
  for (int k = 0; k < 4; ++k) {
    const int e = tid * 4 + k;
    Ps[e >> 5][e & 31] = P[e];
  }
  __syncthreads();
  const int n = tid & 127, half = tid >> 7;   // row n, k range 16*half..+15
  float src[16];
  if (n >= 96) {
    const int j = n - 96;
#pragma unroll
    for (int dd = 0; dd < 16; ++dd) src[dd] = Ps[j][16 * half + dd];
  } else {
    const int sidx = n >> 5;          // 0=k,1=v,2=q
    const int m = n & 31, dh = m & 3, h = m >> 2;
    const int f = dh * 24 + (sidx == 0 ? 8 : (sidx == 1 ? 16 : 0)) + h;
    const float sc = (sidx == 2) ? 0.72134752f : 1.0f;  // 0.5*log2(e) on q
#pragma unroll
    for (int dd = 0; dd < 16; ++dd) {
      float s = 0.f;
      for (int j = 0; j < 32; ++j) s += Ws[f][j] * Ps[j][16 * half + dd];
      src[dd] = s * sc;
    }
  }
  ushort* base = wc2 + (size_t)n6 * 8192;
  const int tile = n >> 4, rr = n & 15;
#pragma unroll
  for (int dd = 0; dd < 16; ++dd) {
    const int k = 16 * half + dd;
    const int off = tile * 512 + ((rr + ((k >> 3) << 4)) << 3) + (k & 7);
    ushort hh, ll;
    split2(src[dd], hh, ll);
    base[off]        = hh;
    base[4096 + off] = ll;
  }
}

// --------------------------------------------------------- per-half x stage
__device__ __forceinline__ void stage_x(Half& hh, int htid,
                                        const float* __restrict__ xbc, int i)
{
  const int t = htid >> 3, dq = (htid & 7) * 4;
  float xv[4];
#pragma unroll
  for (int k = 0; k < 4; ++k) xv[k] = xbc[(t * 32 + dq + k) * 32 + i];
  ushort hs[4], ls[4];
#pragma unroll
  for (int k = 0; k < 4; ++k) split2(xv[k], hs[k], ls[k]);
  const int off = frag_idx(t, dq);
  *(short4*)&hh.xsH[off] = make_short4((short)hs[0], (short)hs[1],
                                       (short)hs[2], (short)hs[3]);
  *(short4*)&hh.xsL[off] = make_short4((short)ls[0], (short)ls[1],
                                       (short)ls[2], (short)ls[3]);
}

// sigmoid(LayerNorm(E + MHSA(E))): thread's 2x2 outputs at rows {g,g+16},
// cols {l,l+16} (g=htid>>4, l=htid&15). lead: this half loads/stores w0.
__device__ __forceinline__ void mhsa_core(SMem& sm, Half& hh, int htid, int half,
                                          const float* __restrict__ w0g, bool lead,
                                          float sig_out[2][2])
{
  const int wv = htid >> 6, lane = htid & 63;
  const int lr = lane & 15, lk = lane >> 4;
  const int mt = wv >> 1;             // token tile (0,1)
  const int qe = wv & 1;              // 0: k/v tiles; 1: q/E tiles
  const int t0 = mt * 16 + lk * 4;    // C rows (4 consecutive tokens)
  f32x4 eC0 = {0.f,0.f,0.f,0.f}, eC1 = {0.f,0.f,0.f,0.f};

  // ---- stage A: E+qkv on the matrix pipe (split-bf16, 3 MFMA/tile) ----
  {
    short8 aH = *(const short8*)&hh.xsH[mt * 512 + lane * 8];
    short8 aL = *(const short8*)&hh.xsL[mt * 512 + lane * 8];
    f32x4 acc[4];
#pragma unroll
    for (int q = 0; q < 4; ++q) {
      const int tile = qe * 4 + q;
      short8 bH = *(const short8*)&sm.u.W[tile * 512 + lane * 8];
      short8 bL = *(const short8*)&sm.u.W[4096 + tile * 512 + lane * 8];
      f32x4 c = {0.f, 0.f, 0.f, 0.f};
      c = __builtin_amdgcn_mfma_f32_16x16x32_bf16(aH, bH, c, 0, 0, 0);
      c = __builtin_amdgcn_mfma_f32_16x16x32_bf16(aH, bL, c, 0, 0, 0);
      c = __builtin_amdgcn_mfma_f32_16x16x32_bf16(aL, bH, c, 0, 0, 0);
      acc[q] = c;
    }
    if (qe == 0) {            // k rows (cc 0..31), v rows
      *(f32x4*)&hh.kT[lr][t0]      = acc[0];
      *(f32x4*)&hh.kT[lr + 16][t0] = acc[1];
      *(f32x4*)&hh.vT[lr][t0]      = acc[2];
      *(f32x4*)&hh.vT[lr + 16][t0] = acc[3];
    } else {                  // q rows -> qS scatter; E -> regs
#pragma unroll
      for (int r = 0; r < 4; ++r) {
        hh.qa.qS[t0 + r][lr]      = acc[0][r];
        hh.qa.qS[t0 + r][lr + 16] = acc[1][r];
      }
      eC0 = acc[2]; eC1 = acc[3];
    }
  }
  // deferred W0 load (HBM latency overlaps barrier + stores)
  float4 w0v = make_float4(0.f, 0.f, 0.f, 0.f);
  if (lead) w0v = *(const float4*)&w0g[htid * 4];
  __syncthreads();                         // barrier 1: stage A done, W dead
  if (qe == 1) {
    *(f32x4*)&sm.u.o.esT[half][lr][t0]      = eC0;   // esT[j][t..t+3]
    *(f32x4*)&sm.u.o.esT[half][lr + 16][t0] = eC1;
  }
  if (lead) { const int e = htid * 4; *(float4*)&sm.u.o.w0s[e >> 5][e & 31] = w0v; }

  // ---- stage 2: attention, 4t x 8s per lane; quad-DPP reductions ----
  {
    const int h2 = htid >> 5, tg2 = (htid >> 2) & 7, sg2 = htid & 3;
    const int ta = 4 * tg2, s0 = 8 * sg2;
    float4 qr0 = *(const float4*)&hh.qa.qS[ta + 0][4 * h2];
    float4 qr1 = *(const float4*)&hh.qa.qS[ta + 1][4 * h2];
    float4 qr2 = *(const float4*)&hh.qa.qS[ta + 2][4 * h2];
    float4 qr3 = *(const float4*)&hh.qa.qS[ta + 3][4 * h2];
    __syncthreads();                       // barrier 1.5: qS dead -> aoF overlay
    const float qa_[4][4] = {
        {qr0.x, qr0.y, qr0.z, qr0.w},
        {qr1.x, qr1.y, qr1.z, qr1.w},
        {qr2.x, qr2.y, qr2.z, qr2.w},
        {qr3.x, qr3.y, qr3.z, qr3.w}};
    v2f sc[4][4];
#pragma unroll
    for (int kk = 0; kk < 4; ++kk)
#pragma unroll
      for (int sp2 = 0; sp2 < 4; ++sp2) sc[kk][sp2] = v2f{0.f, 0.f};
#pragma unroll
    for (int dh = 0; dh < 4; ++dh) {
      const float* kr = &hh.kT[4 * h2 + dh][s0];
      float4 ka = *(const float4*)&kr[0];
      float4 kb = *(const float4*)&kr[4];
      v2f k0{ka.x, ka.y}, k1{ka.z, ka.w}, k2{kb.x, kb.y}, k3{kb.z, kb.w};
#pragma unroll
      for (int kk = 0; kk < 4; ++kk) {
        v2f qv{qa_[kk][dh], qa_[kk][dh]};
        sc[kk][0] = pk_fma(sc[kk][0], qv, k0);
        sc[kk][1] = pk_fma(sc[kk][1], qv, k1);
        sc[kk][2] = pk_fma(sc[kk][2], qv, k2);
        sc[kk][3] = pk_fma(sc[kk][3], qv, k3);
      }
    }
    float inv[4];
#pragma unroll
    for (int kk = 0; kk < 4; ++kk) {
#pragma unroll
      for (int sp2 = 0; sp2 < 4; ++sp2) {
        sc[kk][sp2][0] = exp2f(sc[kk][sp2][0]);
        sc[kk][sp2][1] = exp2f(sc[kk][sp2][1]);
      }
      v2f dv = sc[kk][0] + sc[kk][1];
      v2f dw = sc[kk][2] + sc[kk][3];
      dv += dw;
      float dn = dv[0] + dv[1];
      dn = dpp_add<0xB1>(dn);
      dn = dpp_add<0x4E>(dn);
      inv[kk] = __fdividef(1.0f, dn);
    }
    v2f pv[4][4];
#pragma unroll
    for (int kk = 0; kk < 4; ++kk)
#pragma unroll
      for (int dh = 0; dh < 4; ++dh) pv[kk][dh] = v2f{0.f, 0.f};
#pragma unroll
    for (int dh = 0; dh < 4; ++dh) {
      const float* vr = &hh.vT[4 * h2 + dh][s0];
      float4 va = *(const float4*)&vr[0];
      float4 vb = *(const float4*)&vr[4];
      v2f v0{va.x, va.y}, v1{va.z, va.w}, v2v{vb.x, vb.y}, v3{vb.z, vb.w};
#pragma unroll
      for (int kk = 0; kk < 4; ++kk) {
        pv[kk][dh] = pk_fma(pv[kk][dh], sc[kk][0], v0);
        pv[kk][dh] = pk_fma(pv[kk][dh], sc[kk][1], v1);
        pv[kk][dh] = pk_fma(pv[kk][dh], sc[kk][2], v2v);
        pv[kk][dh] = pk_fma(pv[kk][dh], sc[kk][3], v3);
      }
    }
    float ov[4][4];
#pragma unroll
    for (int kk = 0; kk < 4; ++kk)
#pragma unroll
      for (int dh = 0; dh < 4; ++dh) {
        float o = pv[kk][dh][0] + pv[kk][dh][1];
        o = dpp_add<0xB1>(o);
        o = dpp_add<0x4E>(o);
        ov[kk][dh] = o;
      }
    if (sg2 == 0) {
#pragma unroll
      for (int kk = 0; kk < 4; ++kk) {
        *(float4*)&hh.qa.aoF[ta + kk][4 * h2] = make_float4(
            ov[kk][0] * inv[kk], ov[kk][1] * inv[kk],
            ov[kk][2] * inv[kk], ov[kk][3] * inv[kk]);
      }
    }
  }
  __syncthreads();                         // barrier 2

  // ---- stage 3: proj + residual + LN (DPP) + sigmoid, 2x2 tile ----
  {
    const int g = htid >> 4, l = htid & 15;
    v2f a00{0.f,0.f}, a01{0.f,0.f}, a10{0.f,0.f}, a11{0.f,0.f};
#pragma unroll
    for (int f4 = 0; f4 < 8; ++f4) {
      float4 u0 = *(const float4*)&hh.qa.aoF[g][4 * f4];        // broadcast
      float4 u1 = *(const float4*)&hh.qa.aoF[g + 16][4 * f4];
      float4 w0 = *(const float4*)&sm.u.o.w0s[l][4 * f4];       // w0[j][f]
      float4 w1 = *(const float4*)&sm.u.o.w0s[l + 16][4 * f4];
      a00 = pk_fma(a00, v2f{u0.x, u0.y}, v2f{w0.x, w0.y});
      a00 = pk_fma(a00, v2f{u0.z, u0.w}, v2f{w0.z, w0.w});
      a01 = pk_fma(a01, v2f{u0.x, u0.y}, v2f{w1.x, w1.y});
      a01 = pk_fma(a01, v2f{u0.z, u0.w}, v2f{w1.z, w1.w});
      a10 = pk_fma(a10, v2f{u1.x, u1.y}, v2f{w0.x, w0.y});
      a10 = pk_fma(a10, v2f{u1.z, u1.w}, v2f{w0.z, w0.w});
      a11 = pk_fma(a11, v2f{u1.x, u1.y}, v2f{w1.x, w1.y});
      a11 = pk_fma(a11, v2f{u1.z, u1.w}, v2f{w1.z, w1.w});
    }
    float rr[2][2];
    rr[0][0] = a00[0] + a00[1] + sm.u.o.esT[half][l][g];
    rr[0][1] = a01[0] + a01[1] + sm.u.o.esT[half][l + 16][g];
    rr[1][0] = a10[0] + a10[1] + sm.u.o.esT[half][l][g + 16];
    rr[1][1] = a11[0] + a11[1] + sm.u.o.esT[half][l + 16][g + 16];
    float s1a = rr[0][0] + rr[0][1], s1b = rr[1][0] + rr[1][1];
    float s2a = rr[0][0]*rr[0][0] + rr[0][1]*rr[0][1];
    float s2b = rr[1][0]*rr[1][0] + rr[1][1]*rr[1][1];
    s1a = dpp_add<0xB1>(s1a); s1a = dpp_add<0x4E>(s1a);
    s1a = dpp_add<0x124>(s1a); s1a = dpp_add<0x128>(s1a);
    s2a = dpp_add<0xB1>(s2a); s2a = dpp_add<0x4E>(s2a);
    s2a = dpp_add<0x124>(s2a); s2a = dpp_add<0x128>(s2a);
    s1b = dpp_add<0xB1>(s1b); s1b = dpp_add<0x4E>(s1b);
    s1b = dpp_add<0x124>(s1b); s1b = dpp_add<0x128>(s1b);
    s2b = dpp_add<0xB1>(s2b); s2b = dpp_add<0x4E>(s2b);
    s2b = dpp_add<0x124>(s2b); s2b = dpp_add<0x128>(s2b);
    const float mua = s1a * (1.0f / 32.0f), mub = s1b * (1.0f / 32.0f);
    const float ra = rsqrtf(s2a * (1.0f / 32.0f) - mua * mua + 1e-5f);
    const float rb = rsqrtf(s2b * (1.0f / 32.0f) - mub * mub + 1e-5f);
    const float g0 = hh.qa.qS[l][32],      b0 = hh.qa.qS[l][33];  // cols preserved
    const float g1 = hh.qa.qS[l + 16][32], b1 = hh.qa.qS[l + 16][33];
    sig_out[0][0] = __fdividef(1.0f, 1.0f + exp2f(-((rr[0][0] - mua) * ra * g0 + b0)));
    sig_out[0][1] = __fdividef(1.0f, 1.0f + exp2f(-((rr[0][1] - mua) * ra * g1 + b1)));
    sig_out[1][0] = __fdividef(1.0f, 1.0f + exp2f(-((rr[1][0] - mub) * rb * g0 + b0)));
    sig_out[1][1] = __fdividef(1.0f, 1.0f + exp2f(-((rr[1][1] - mub) * rb * g1 + b1)));
  }
}

__global__ __launch_bounds__(256, 4) void phase1_kernel(
    const float* __restrict__ x, const ushort* __restrict__ wc2,
    const float* __restrict__ w0_x,
    const float* __restrict__ g_x, const float* __restrict__ b_x,
    bf16* __restrict__ gates)
{
  __shared__ SMem sm;
  const int tid = threadIdx.x;
  Half& hh = sm.h[0];
  const int n = blockIdx.x;          // 768 = 256*3
  const int c = n % 3, b = n / 3;
  const float* xbc = x + (size_t)(b * 3 + 2) * 32768;   // channel 2
  {  // W image: 64B/thread
    const float4* src = (const float4*)(wc2 + (size_t)(3 + c) * 8192 + tid * 32);
    float4 r0 = src[0], r1 = src[1], r2 = src[2], r3 = src[3];
    float4* dst = (float4*)(sm.u.W + tid * 32);
    dst[0] = r0; dst[1] = r1; dst[2] = r2; dst[3] = r3;
  }
  stage_x(hh, tid, xbc, 31);
  if (tid < 32) {
    const float L2E = 1.44269504f;
    hh.qa.qS[tid][32] = g_x[tid] * L2E;
    hh.qa.qS[tid][33] = b_x[tid] * L2E;
  }
  __syncthreads();
  float sig[2][2];
  mhsa_core(sm, hh, tid, 0, w0_x + c * 1024, true, sig);
  const int g = tid >> 4, l = tid & 15;
#pragma unroll
  for (int u = 0; u < 2; ++u)
#pragma unroll
    for (int v = 0; v < 2; ++v)
      gates[((c * 256 + b) * 32 + g + 16 * u) * 32 + l + 16 * v] =
          __float2bfloat16(sig[u][v]);
}

__global__ __launch_bounds__(512, 6) void phase2_kernel(
    const float* __restrict__ x, const ushort* __restrict__ wc2,
    const float* __restrict__ w0_y,
    const float* __restrict__ g_y, const float* __restrict__ b_y,
    const bf16* __restrict__ gates, float* __restrict__ out)
{
  __shared__ SMem sm;
  const int tid = threadIdx.x;
  const int half = tid >> 8, htid = tid & 255;
  Half& hh = sm.h[half];
  const int n = blockIdx.x;                    // 12288
  const int p = (n & 7) * 1536 + (n >> 3);     // XCD swizzle (12288 % 8 == 0)
  const int ii = p & 15, bc = p >> 4;
  const int c = bc % 3, b = bc / 3;
  const int i = ii * 2 + half;
  const float* xbc = x + (size_t)bc * 32768;
  {  // W image: 32B/thread across full block
    const float4* src = (const float4*)(wc2 + (size_t)c * 8192 + tid * 16);
    float4 r0 = src[0], r1 = src[1];
    float4* dst = (float4*)(sm.u.W + tid * 16);
    dst[0] = r0; dst[1] = r1;
  }
  stage_x(hh, htid, xbc, i);
  if (htid < 32) {
    const float L2E = 1.44269504f;
    hh.qa.qS[htid][32] = g_y[htid] * L2E;
    hh.qa.qS[htid][33] = b_y[htid] * L2E;
    hh.kT[htid][32] =
        __bfloat162float(gates[((c * 256 + b) * 32 + i) * 32 + htid]);
  }
  __syncthreads();
  float sig[2][2];
  mhsa_core(sm, hh, htid, half, w0_y + c * 1024, half == 0, sig);
  const int g = htid >> 4, l = htid & 15;
  float* ob = out + (size_t)bc * 32768 + i;
#pragma unroll
  for (int u = 0; u < 2; ++u) {
    const int r = g + 16 * u;
    const float sgv = hh.kT[r][32];            // sig(ys_c[b, i, t])
#pragma unroll
    for (int v = 0; v < 2; ++v) {
      const int cc = l + 16 * v;
      const int off = frag_idx(r, cc);
      const float xvv = __uint_as_float((uint)hh.xsH[off] << 16) +
                        __uint_as_float((uint)hh.xsL[off] << 16);
      ob[(r * 32 + cc) * 32] = sgv * sig[u][v] * xvv;
    }
  }
}

extern "C" void kernel_launch(void* const* d_in, const int* in_sizes, int n_in,
                              void* d_out, int out_size, void* d_ws, size_t ws_size,
                              hipStream_t stream) {
  const float* x      = (const float*)d_in[0];
  const float* pos_y  = (const float*)d_in[1];
  const float* wqvk_y = (const float*)d_in[2];
  const float* w0_y   = (const float*)d_in[3];
  const float* g_y    = (const float*)d_in[4];
  const float* b_y    = (const float*)d_in[5];
  const float* wqvk_x = (const float*)d_in[6];
  const float* w0_x   = (const float*)d_in[7];
  const float* g_x    = (const float*)d_in[8];
  const float* b_x    = (const float*)d_in[9];
  bf16*   gates = (bf16*)d_ws;                             // 1.5 MB
  ushort* wc2   = (ushort*)((char*)d_ws + 1572864);        // 6*16384 B

  hipLaunchKernelGGL(wc_kernel, dim3(6), dim3(256), 0, stream,
                     pos_y, wqvk_y, wqvk_x, wc2);
  hipLaunchKernelGGL(phase1_kernel, dim3(768), dim3(256), 0, stream,
                     x, wc2, w0_x, g_x, b_x, gates);
  hipLaunchKernelGGL(phase2_kernel, dim3(12288), dim3(512), 0, stream,
                     x, wc2, w0_y, g_y, b_y, gates, (float*)d_out);
}